// Round 12
// baseline (190.234 us; speedup 1.0000x reference)
//
#include <hip/hip_runtime.h>
#include <hip/hip_bf16.h>
#include <math.h>

#define NB 64        // B
#define NH 8         // H
#define NE 65536     // E
#define ND 256       // N2
#define IDX_STRIDE 2048
#define WSL 16       // keys per wave in score_agg
#define NPB 32       // blocks (partials) per b: 64 keys/block

// ============ k1: fused prep (blocks 0-63) + bucket (blocks 64-127)
__global__ __launch_bounds__(256) void prep_bucket_k(const float* __restrict__ gq,
    const float* __restrict__ Wq, const float* __restrict__ bq,
    const float* __restrict__ Wk, const float* __restrict__ bk,
    const int* __restrict__ batch,
    float* __restrict__ t2, float* __restrict__ c_ws,
    int* __restrict__ idx, int* __restrict__ counts)
{
  __shared__ float xs[ND];
  __shared__ float qs[ND];
  __shared__ int sc[256];
  const int tid = threadIdx.x;

  if (blockIdx.x < 64) {
    const int b = blockIdx.x;
    const int j = tid;
    xs[j] = gq[(size_t)b * ND + j];
    __syncthreads();
    float acc = bq[j];
    const float4* wp = (const float4*)(Wq + (size_t)j * ND);
    #pragma unroll 8
    for (int k4 = 0; k4 < ND / 4; ++k4) {
      float4 w = wp[k4];
      float4 x = *(const float4*)&xs[k4 * 4];
      acc = fmaf(x.x, w.x, acc);
      acc = fmaf(x.y, w.y, acc);
      acc = fmaf(x.z, w.z, acc);
      acc = fmaf(x.w, w.w, acc);
    }
    qs[j] = acc;
    __syncthreads();
    float th[NH];
    #pragma unroll
    for (int h = 0; h < NH; ++h) th[h] = 0.f;
    #pragma unroll
    for (int h = 0; h < NH; ++h) {
      #pragma unroll 8
      for (int dd = 0; dd < 32; ++dd)
        th[h] = fmaf(qs[h * 32 + dd], Wk[(size_t)(h * 32 + dd) * ND + j], th[h]);
    }
    float* tp = t2 + ((size_t)b * ND + j) * NH;
    #pragma unroll
    for (int h = 0; h < NH; ++h) tp[h] = th[h];
    if (j < NH) {
      float c = 0.f;
      #pragma unroll
      for (int dd = 0; dd < 32; ++dd)
        c = fmaf(qs[j * 32 + dd], bk[j * 32 + dd], c);
      c_ws[b * NH + j] = c;
    }
  } else {
    const int b = blockIdx.x - 64;
    const int4* b4 = (const int4*)batch;
    int c = 0;
    #pragma unroll 4
    for (int i = 0; i < 64; ++i) {
      const int4 v = b4[tid * 64 + i];
      c += (v.x == b) + (v.y == b) + (v.z == b) + (v.w == b);
    }
    sc[tid] = c;
    __syncthreads();
    for (int s = 1; s < 256; s <<= 1) {
      const int t = (tid >= s) ? sc[tid - s] : 0;
      __syncthreads();
      sc[tid] += t;
      __syncthreads();
    }
    int pos = sc[tid] - c;
    int* __restrict__ myidx = idx + b * IDX_STRIDE;
    #pragma unroll 4
    for (int i = 0; i < 64; ++i) {
      const int4 v = b4[tid * 64 + i];
      const int e0 = tid * 256 + i * 4;
      if (v.x == b) { if (pos < IDX_STRIDE) myidx[pos] = e0 + 0; ++pos; }
      if (v.y == b) { if (pos < IDX_STRIDE) myidx[pos] = e0 + 1; ++pos; }
      if (v.z == b) { if (pos < IDX_STRIDE) myidx[pos] = e0 + 2; ++pos; }
      if (v.w == b) { if (pos < IDX_STRIDE) myidx[pos] = e0 + 3; ++pos; }
    }
    if (tid == 255) counts[b] = sc[255];
  }
}

// ============ k2: fused score+aggregate, phase-split, branch-free unroll.
// Wave = 16 keys. Padded keys use row 0 with weight forced to 0; (m,l) is
// reference-consistent so downstream combine is exact.
__global__ __launch_bounds__(256) void score_agg_k(const float* __restrict__ lk,
    const float* __restrict__ lv, const int* __restrict__ idx,
    const int* __restrict__ counts, const float* __restrict__ t2,
    const float* __restrict__ c_ws, float* __restrict__ score2,
    float* __restrict__ ml_ws, float* __restrict__ pagg)
{
  __shared__ float s_acc[3][NH][260];
  __shared__ float s_mlb[4][NH][2];
  const int b = blockIdx.x >> 5;
  const int blk = blockIdx.x & 31;
  const int tid = threadIdx.x;
  const int wid = tid >> 6, lane = tid & 63;
  const int count = min(counts[b], IDX_STRIDE);
  if (blk * 64 >= count) return;                // block-uniform exit
  const int j0 = (blk * 4 + wid) * WSL;
  const int nk = min(WSL, count - j0);          // may be <= 0 for wid>0

  float t2s[32];
  {
    const float4* tp = (const float4*)(t2 + ((size_t)b * ND + lane * 4) * NH);
    #pragma unroll
    for (int k = 0; k < 8; ++k) {
      float4 v = tp[k];
      t2s[4 * k + 0] = v.x; t2s[4 * k + 1] = v.y;
      t2s[4 * k + 2] = v.z; t2s[4 * k + 3] = v.w;
    }
  }
  const float c8 = c_ws[b * NH + (lane & 7)];
  const int eidx = (lane < nk) ? idx[b * IDX_STRIDE + j0 + lane] : 0;

  // broadcast all key ids (padded -> row 0, safe)
  int e_t[WSL];
  #pragma unroll
  for (int t = 0; t < WSL; ++t) e_t[t] = __shfl(eidx, t);

  // ---------- phase 1: all lk loads upfront, then 16 independent reduces
  float4 xr[WSL];
  #pragma unroll
  for (int t = 0; t < WSL; ++t)
    xr[t] = *(const float4*)(lk + (size_t)e_t[t] * ND + lane * 4);

  float sw[WSL];
  float m = -INFINITY, l = 0.f;
  #pragma unroll
  for (int t = 0; t < WSL; ++t) {
    const float4 x4 = xr[t];
    float p[8];
    #pragma unroll
    for (int h = 0; h < 8; ++h)
      p[h] = fmaf(x4.x, t2s[0 * 8 + h], 0.f);
    #pragma unroll
    for (int h = 0; h < 8; ++h) {
      p[h] = fmaf(x4.y, t2s[1 * 8 + h], p[h]);
      p[h] = fmaf(x4.z, t2s[2 * 8 + h], p[h]);
      p[h] = fmaf(x4.w, t2s[3 * 8 + h], p[h]);
    }
    // register-halving butterfly: head h lands on lanes with (lane&7)==h
    float q[4];
    #pragma unroll
    for (int i = 0; i < 4; ++i) {
      const float keep = (lane & 4) ? p[i + 4] : p[i];
      const float send = (lane & 4) ? p[i] : p[i + 4];
      q[i] = keep + __shfl_xor(send, 4);
    }
    float u[2];
    #pragma unroll
    for (int i = 0; i < 2; ++i) {
      const float keep = (lane & 2) ? q[i + 2] : q[i];
      const float send = (lane & 2) ? q[i] : q[i + 2];
      u[i] = keep + __shfl_xor(send, 2);
    }
    float v;
    {
      const float keep = (lane & 1) ? u[1] : u[0];
      const float send = (lane & 1) ? u[0] : u[1];
      v = keep + __shfl_xor(send, 1);
    }
    v += __shfl_xor(v, 8);
    v += __shfl_xor(v, 16);
    v += __shfl_xor(v, 32);
    v += c8;                    // complete score for head lane&7, all lanes
    sw[t] = v;
    if (t < nk) {
      m = fmaxf(m, v);
      if (lane < 8)
        score2[((size_t)b * IDX_STRIDE + j0 + t) * NH + lane] = v;
    }
  }

  // ---------- weights: lane-parallel exp; padded keys -> weight 0
  #pragma unroll
  for (int t = 0; t < WSL; ++t) {
    const float w = (t < nk) ? __expf(sw[t] - m) : 0.f;
    sw[t] = w;
    l += w;
  }

  // ---------- phase 2: all lv loads upfront, then fma stream
  float4 yr[WSL];
  #pragma unroll
  for (int t = 0; t < WSL; ++t)
    yr[t] = *(const float4*)(lv + (size_t)e_t[t] * ND + lane * 4);

  float4 acc[NH];
  #pragma unroll
  for (int h = 0; h < NH; ++h) acc[h] = (float4){0.f, 0.f, 0.f, 0.f};
  #pragma unroll
  for (int t = 0; t < WSL; ++t) {
    const float4 y4 = yr[t];
    float wl[8];
    #pragma unroll
    for (int h = 0; h < 8; ++h) wl[h] = __shfl(sw[t], h);
    #pragma unroll
    for (int h = 0; h < 8; ++h) {
      acc[h].x = fmaf(wl[h], y4.x, acc[h].x);
      acc[h].y = fmaf(wl[h], y4.y, acc[h].y);
      acc[h].z = fmaf(wl[h], y4.z, acc[h].z);
      acc[h].w = fmaf(wl[h], y4.w, acc[h].w);
    }
  }

  // ---------- block reduce across 4 waves with rescale
  if (lane < 8) {
    s_mlb[wid][lane][0] = m;
    s_mlb[wid][lane][1] = l;
  }
  if (wid != 0) {
    #pragma unroll
    for (int h = 0; h < NH; ++h)
      *(float4*)&s_acc[wid - 1][h][lane * 4] = acc[h];
  }
  __syncthreads();
  if (wid == 0) {
    #pragma unroll
    for (int h = 0; h < NH; ++h) {
      float Mb = s_mlb[0][h][0];            // wave0 nk>=1 -> finite
      #pragma unroll
      for (int w = 1; w < 4; ++w) Mb = fmaxf(Mb, s_mlb[w][h][0]);
      const float r0 = __expf(s_mlb[0][h][0] - Mb);
      float4 a;
      a.x = acc[h].x * r0; a.y = acc[h].y * r0;
      a.z = acc[h].z * r0; a.w = acc[h].w * r0;
      float lb = s_mlb[0][h][1] * r0;
      #pragma unroll
      for (int w = 1; w < 4; ++w) {
        const float rw = __expf(s_mlb[w][h][0] - Mb);   // -inf -> 0 (empty)
        lb = fmaf(s_mlb[w][h][1], rw, lb);
        const float4 aw = *(const float4*)&s_acc[w - 1][h][lane * 4];
        a.x = fmaf(aw.x, rw, a.x); a.y = fmaf(aw.y, rw, a.y);
        a.z = fmaf(aw.z, rw, a.z); a.w = fmaf(aw.w, rw, a.w);
      }
      *(float4*)(pagg + (((size_t)b * NPB + blk) * NH + h) * ND + lane * 4) = a;
      if (lane == 0) {
        ml_ws[(((size_t)b * NPB + blk) * NH + h) * 2 + 0] = Mb;
        ml_ws[(((size_t)b * NPB + blk) * NH + h) * 2 + 1] = lb;
      }
    }
  }
}

// ============ k3: combine per-block (m,l) -> Minv[b][h] + scale[b][blk][h]
__global__ __launch_bounds__(256) void combine_k(const float* __restrict__ ml_ws,
    const int* __restrict__ counts, float* __restrict__ Minv_ws,
    float* __restrict__ scale_ws)
{
  const int b = blockIdx.x;
  const int tid = threadIdx.x;
  const int h = tid >> 5, i = tid & 31;       // one (h, blk) per thread
  const int count = min(counts[b], IDX_STRIDE);
  const int nblk = min((count + 63) / 64, NPB);

  float m = -INFINITY, l = 0.f;
  float mi = -INFINITY;
  if (i < nblk) {
    mi = ml_ws[(((size_t)b * NPB + i) * NH + h) * 2 + 0];
    l = ml_ws[(((size_t)b * NPB + i) * NH + h) * 2 + 1];
    m = mi;
  }
  #pragma unroll
  for (int off = 1; off <= 16; off <<= 1) {
    const float mo = __shfl_xor(m, off);
    const float lo = __shfl_xor(l, off);
    const float mn = fmaxf(m, mo);
    if (mn == -INFINITY) { l = 0.f; }
    else { l = l * __expf(m - mn) + lo * __expf(mo - mn); }
    m = mn;
  }
  const float inv = (l > 0.f) ? 1.f / l : 0.f;
  scale_ws[((size_t)b * NPB + i) * NH + h] =
      (i < nblk) ? __expf(mi - m) * inv : 0.f;
  if (i == 0) {
    Minv_ws[((size_t)b * NH + h) * 2 + 0] = m;
    Minv_ws[((size_t)b * NH + h) * 2 + 1] = inv;
  }
}

// ============ k4: attn_write: zero stream + one barrier + L2-hot scatter
__global__ __launch_bounds__(256) void attn_write_k(
    const float* __restrict__ score2, const float* __restrict__ Minv_ws,
    const int* __restrict__ idx, const int* __restrict__ counts,
    float* __restrict__ attn_out)
{
  const int hb = blockIdx.x;          // h*64 + b
  const int h = hb >> 6, b = hb & 63;
  const int tid = threadIdx.x;
  const int count = min(counts[b], IDX_STRIDE);

  const float M = Minv_ws[((size_t)b * NH + h) * 2 + 0];
  const float inv = Minv_ws[((size_t)b * NH + h) * 2 + 1];

  float* __restrict__ arow = attn_out + (size_t)hb * NE;
  float4* __restrict__ arow4 = (float4*)arow;
  const float4 z4 = {0.f, 0.f, 0.f, 0.f};
  for (int c = tid; c < NE / 4; c += 256) arow4[c] = z4;
  __syncthreads();   // drains vmcnt -> zeros committed before scatter

  const int* __restrict__ myidx = idx + b * IDX_STRIDE;
  for (int j = tid; j < count; j += 256)
    arow[myidx[j]] =
        __expf(score2[((size_t)b * IDX_STRIDE + j) * NH + h] - M) * inv;
}

// ============ k5: final: agg = sum_blk pagg*scale; Wv (+bv*ind); Wo (+bo)
__global__ __launch_bounds__(256) void final_k(const float* __restrict__ pagg,
    const float* __restrict__ scale_ws, const int* __restrict__ counts,
    const float* __restrict__ Wv, const float* __restrict__ bv,
    const float* __restrict__ Wo, const float* __restrict__ bo,
    float* __restrict__ xout)
{
  __shared__ float s_scale[NH][NPB];
  __shared__ float agg[NH][260];
  __shared__ float opre[ND];
  const int b = blockIdx.x;
  const int tid = threadIdx.x;
  const int count = min(counts[b], IDX_STRIDE);
  const int nblk = min((count + 63) / 64, NPB);

  {
    const int h = tid >> 5, i = tid & 31;
    s_scale[h][i] = scale_ws[((size_t)b * NPB + i) * NH + h];
  }
  __syncthreads();

  #pragma unroll
  for (int h = 0; h < NH; ++h) {
    float a = 0.f;
    for (int s = 0; s < nblk; ++s)
      a = fmaf(pagg[(((size_t)b * NPB + s) * NH + h) * ND + tid],
               s_scale[h][s], a);
    agg[h][tid] = a;
  }
  const float ind = (count > 0) ? 1.f : 0.f;
  __syncthreads();

  {
    const int h = tid >> 5;
    float acc = bv[tid] * ind;
    const float4* wp = (const float4*)(Wv + (size_t)tid * ND);
    #pragma unroll 8
    for (int d4 = 0; d4 < ND / 4; ++d4) {
      float4 w = wp[d4];
      float4 g = *(const float4*)&agg[h][4 * d4];
      acc = fmaf(w.x, g.x, acc);
      acc = fmaf(w.y, g.y, acc);
      acc = fmaf(w.z, g.z, acc);
      acc = fmaf(w.w, g.w, acc);
    }
    opre[tid] = acc;
  }
  __syncthreads();
  {
    float acc = bo[tid];
    const float4* wp = (const float4*)(Wo + (size_t)tid * ND);
    #pragma unroll 8
    for (int d4 = 0; d4 < ND / 4; ++d4) {
      float4 w = wp[d4];
      float4 g = *(const float4*)&opre[4 * d4];
      acc = fmaf(w.x, g.x, acc);
      acc = fmaf(w.y, g.y, acc);
      acc = fmaf(w.z, g.z, acc);
      acc = fmaf(w.w, g.w, acc);
    }
    xout[(size_t)b * ND + tid] = acc;
  }
}

extern "C" void kernel_launch(void* const* d_in, const int* in_sizes, int n_in,
                              void* d_out, int out_size, void* d_ws, size_t ws_size,
                              hipStream_t stream)
{
  const float* gq   = (const float*)d_in[0];
  const float* lk   = (const float*)d_in[1];
  const float* lv   = (const float*)d_in[2];
  const int*  batch = (const int*)d_in[3];
  const float* Wq = (const float*)d_in[4];
  const float* bq = (const float*)d_in[5];
  const float* Wk = (const float*)d_in[6];
  const float* bk = (const float*)d_in[7];
  const float* Wv = (const float*)d_in[8];
  const float* bv = (const float*)d_in[9];
  const float* Wo = (const float*)d_in[10];
  const float* bo = (const float*)d_in[11];

  float* xout = (float*)d_out;                          // [64,256]
  float* attn_out = xout + (size_t)NB * ND;             // [H,B,E]

  float* t2       = (float*)d_ws;                                   // 64*256*8
  float* c_ws     = t2 + (size_t)NB * ND * NH;                      // 512
  float* score2   = c_ws + (size_t)NB * NH;                         // 64*2048*8
  float* ml_ws    = score2 + (size_t)NB * IDX_STRIDE * NH;          // 64*32*8*2
  float* scale_ws = ml_ws + (size_t)NB * NPB * NH * 2;              // 64*32*8
  float* Minv_ws  = scale_ws + (size_t)NB * NPB * NH;               // 64*8*2
  float* pagg     = Minv_ws + (size_t)NB * NH * 2;                  // 64*32*8*256
  int*   idx      = (int*)(pagg + (size_t)NB * NPB * NH * ND);      // 64*2048
  int*   counts   = idx + (size_t)NB * IDX_STRIDE;                  // 64

  prep_bucket_k<<<128, 256, 0, stream>>>(gq, Wq, bq, Wk, bk, batch,
                                         t2, c_ws, idx, counts);
  score_agg_k<<<NB * NPB, 256, 0, stream>>>(lk, lv, idx, counts, t2, c_ws,
                                            score2, ml_ws, pagg);
  combine_k<<<NB, 256, 0, stream>>>(ml_ws, counts, Minv_ws, scale_ws);
  attn_write_k<<<NH * NB, 256, 0, stream>>>(score2, Minv_ws, idx, counts, attn_out);
  final_k<<<NB, 256, 0, stream>>>(pagg, scale_ws, counts, Wv, bv, Wo, bo, xout);
}